// Round 8
// baseline (257.981 us; speedup 1.0000x reference)
//
#include <hip/hip_runtime.h>
#include <math.h>

#define B_    32
#define F_    4000
#define L_    65
#define N_    129           // 2L-1, odd irfft length
#define HOP_  64
#define K_    192           // hop + 2L - 2
#define GF_   4             // frames per wave (R8: 8 -> 4, doubles wave count)
#define WAVES_ 4
#define OUTLEN_ ((F_-1)*HOP_ + K_)   // 256128
#define GAIN_ 0.01f
#define BLKS_PER_B_ (F_/(GF_*WAVES_))   // 250

// Math (see earlier rounds): ir[m]=win[m]*ir_raw[|m-64|]; frames = conv(2n-1, ir);
// OLA hop 64. Phase A: Chebyshev cosine recurrence, reseeded every 16 from table.
//
// R8 delta vs R7 (stall attack; dataflow + sched_barrier fences unchanged):
//  1. Phase B accumulators split into 4 independent chains (dep 64 -> 16 FMAs).
//  2. j processed in pairs: all three taps become adjacent-dword pairs ->
//     3 ds_read2_b32 per 2 j  (DS instr/frame 128 -> 96).
//  3. GF 8 -> 4: 8000 blocks / 32000 waves — shorter serial streams, more
//     wave-level overlap for the same total work.

__global__ __launch_bounds__(256, 2) void filtered_noise_kernel(
    const float* __restrict__ nfilt,   // [B,F,65]
    const float* __restrict__ noise,   // [B,F,64]
    float* __restrict__ out)           // [B, OUTLEN]
{
    __shared__ float costab[N_];
    __shared__ float irp[WAVES_][260];  // per-wave: [0,64)=0, [64,192]=ir, (192..)=0

    const int tid  = threadIdx.x;
    const int lane = tid & 63;
    const int wid  = __builtin_amdgcn_readfirstlane(tid >> 6);

    for (int i = tid; i < N_; i += 256)
        costab[i] = (float)cos((double)i * (2.0 * M_PI / 129.0));

    float* ir = irp[wid];
    for (int i = lane; i < 260; i += 64) ir[i] = 0.0f;

    __syncthreads();   // costab + pad init; the only block barrier

    const int b  = blockIdx.x / BLKS_PER_B_;
    const int g  = (blockIdx.x % BLKS_PER_B_) * WAVES_ + wid;  // group in [0,1000)
    const int f0 = g * GF_;

    const int   t     = lane + 1;            // lane computes ir_raw[t], t=1..64
    const float scale = 2.0f / 129.0f;
    const float cA = 0.5f * (1.0f - costab[64 - t]) * scale;   // win[64-t]*(2/129)
    const float cB = 0.5f * (1.0f - costab[64 + t]) * scale;   // win[64+t]*(2/129)
    const float c0 = 0.5f * (1.0f - costab[64]) * scale;       // win[64]  *(2/129)

    // Chebyshev seeds from the exact table (per-lane, once)
    const float c1 = costab[t];
    const float tc = 2.0f * c1;
    float sdA[4], sdB[4];
    sdA[0] = 1.0f;                 sdB[0] = c1;
    sdA[1] = costab[(16*t) % N_];  sdB[1] = costab[(17*t) % N_];
    sdA[2] = costab[(32*t) % N_];  sdB[2] = costab[(33*t) % N_];
    sdA[3] = costab[(48*t) % N_];  sdB[3] = costab[(49*t) % N_];

    const float* Xf = nfilt + (size_t)(b * F_ + f0) * L_;          // uniform
    const float* Zf = noise + (size_t)(b * F_ + f0) * HOP_ + lane; // per-lane
    float*       op = out + (size_t)b * OUTLEN_ + (size_t)f0 * HOP_ + lane;

    const float* pb = ir + lane;   // fixed DS base; offsets are compile-time

    // rolling slots, each as 4 independent partial chains:
    // wa = slot i, wb = slot i+1, wc = slot i+2
    float wa[4] = {0,0,0,0}, wb[4] = {0,0,0,0}, wc[4] = {0,0,0,0};

    #pragma unroll 1
    for (int i = 0; i < GF_; ++i) {
        // coalesced per-lane noise load (vmcnt; latency hidden behind Phase A)
        float zc = Zf[0];
        zc = fmaf(2.0f, zc, -1.0f);

        // ---- Phase A: a = 0.5*X0 + sum_{k=1..64} X[k]*cos(k*t*th) ----
        float x0 = Xf[0];
        float a = 0.5f * x0;
        float s = 0.5f * x0;
        #pragma unroll
        for (int c = 0; c < 4; ++c) {
            float ckm1 = sdA[c], ck = sdB[c];
            float aa = 0.0f, ss = 0.0f;
            #pragma unroll
            for (int q = 0; q < 16; ++q) {
                float x = Xf[c * 16 + q + 1];     // wave-uniform -> s_load
                aa = fmaf(x, ck, aa);
                ss += x;
                float cn = fmaf(tc, ck, -ckm1);   // Chebyshev step
                ckm1 = ck; ck = cn;
            }
            a += aa; s += ss;
        }

        // ---- windowed IR -> per-wave LDS; order pinned (cross-lane RAW) ----
        __builtin_amdgcn_sched_barrier(0);
        ir[128 - t] = cA * a;
        ir[128 + t] = cB * a;
        if (lane == 0) ir[128] = c0 * s;
        __builtin_amdgcn_sched_barrier(0);

        // ---- Phase B: j in pairs; 3 adjacent-dword pair loads (ds_read2);
        //      4 independent accumulator chains (c = p & 3) ----
        #pragma unroll
        for (int p = 0; p < 32; ++p) {
            const int j = 2 * p;
            const int c = p & 3;
            float nj0 = __uint_as_float(
                __builtin_amdgcn_readlane(__float_as_uint(zc), j));
            float nj1 = __uint_as_float(
                __builtin_amdgcn_readlane(__float_as_uint(zc), j + 1));
            float a1 = pb[63 - j],  a0 = pb[64 - j];    // ds_read2_b32
            float b1 = pb[127 - j], b0 = pb[128 - j];   // ds_read2_b32
            float d1 = pb[191 - j], d0 = pb[192 - j];   // ds_read2_b32
            wa[c] = fmaf(nj0, a0, wa[c]);  wa[c] = fmaf(nj1, a1, wa[c]);
            wb[c] = fmaf(nj0, b0, wb[c]);  wb[c] = fmaf(nj1, b1, wb[c]);
            wc[c] = fmaf(nj0, d0, wc[c]);  wc[c] = fmaf(nj1, d1, wc[c]);
        }
        __builtin_amdgcn_sched_barrier(0);   // WAR fence vs next frame's IR writes

        // ---- retire slot i (i<2 overlaps previous group -> atomic) ----
        float va = ((wa[0] + wa[1]) + (wa[2] + wa[3])) * GAIN_;
        if (i < 2) atomicAdd(op, va); else *op = va;
        op += HOP_;
        #pragma unroll
        for (int c = 0; c < 4; ++c) { wa[c] = wb[c]; wb[c] = wc[c]; wc[c] = 0.0f; }
        Xf += L_; Zf += HOP_;
    }
    // tails: slot GF (wa after roll) and slot GF+1 (wb) overlap the next group
    atomicAdd(op,        ((wa[0] + wa[1]) + (wa[2] + wa[3])) * GAIN_);
    atomicAdd(op + HOP_, ((wb[0] + wb[1]) + (wb[2] + wb[3])) * GAIN_);

}

extern "C" void kernel_launch(void* const* d_in, const int* in_sizes, int n_in,
                              void* d_out, int out_size, void* d_ws, size_t ws_size,
                              hipStream_t stream) {
    const float* nfilt = (const float*)d_in[0];
    const float* noise = (const float*)d_in[1];
    float* out = (float*)d_out;

    hipMemsetAsync(d_out, 0, (size_t)out_size * sizeof(float), stream);

    dim3 grid(B_ * BLKS_PER_B_);   // 8000 blocks
    dim3 block(256);
    filtered_noise_kernel<<<grid, block, 0, stream>>>(nfilt, noise, out);
}

// Round 9
// 213.086 us; speedup vs baseline: 1.2107x; 1.2107x over previous
//
#include <hip/hip_runtime.h>
#include <hip/hip_fp16.h>
#include <math.h>

#define B_    32
#define F_    4000
#define L_    65
#define N_    129           // 2L-1, odd irfft length
#define HOP_  64
#define K_    192           // hop + 2L - 2
#define GF_   8             // frames per wave (back to proven R7 config)
#define WAVES_ 4
#define OUTLEN_ ((F_-1)*HOP_ + K_)   // 256128
#define GAIN_ 0.01f
#define BLKS_PER_B_ (F_/(GF_*WAVES_))   // 125
#define CPH_  260           // halves per copy (positions 0..259, zero-padded)

// Math (see earlier rounds): ir[m]=win[m]*ir_raw[|m-64|], support m in [0,128];
// frames = conv(2n-1, ir); OLA hop 64. Phase A: Chebyshev recurrence.
//
// R9 delta vs R7 (attack the REAL bottleneck): R8 accounting showed the kernel
// is LDS-pipe-throughput-bound: 128 DS instr/frame x ~7 cy x 500 frames/CU
// ~ 184us ~ measured. Fix: IR stored in LDS as f16, TWO copies (copyO shifted
// +1 tap). Lane parity picks the copy so that the 2-tap dword for j-pair
// (2p+1, 2p) is dword-aligned for every lane, with uniform half->j mapping:
// low half = tap(j=2p+1), high = tap(j=2p). Phase B: 96 dword loads/frame
// (ds_read2-mergeable, all compile-time imm offsets from one per-lane base)
// ~= 390 cy/frame LDS vs 880 before. FMA via (float)half * z -> v_fma_mix_f32.
// Precision: f16 taps add ~5e-6 to out (threshold 2e-4).

__global__ __launch_bounds__(256, 2) void filtered_noise_kernel(
    const float* __restrict__ nfilt,   // [B,F,65]
    const float* __restrict__ noise,   // [B,F,64]
    float* __restrict__ out)           // [B, OUTLEN]
{
    __shared__ float costab[N_];
    __shared__ __half hbuf[WAVES_][2][CPH_];  // [copyE(+64), copyO(+65)] per wave

    const int tid  = threadIdx.x;
    const int lane = tid & 63;
    const int wid  = __builtin_amdgcn_readfirstlane(tid >> 6);

    for (int i = tid; i < N_; i += 256)
        costab[i] = (float)cos((double)i * (2.0 * M_PI / 129.0));

    __half* hb = &hbuf[wid][0][0];
    for (int i = lane; i < 2 * CPH_; i += 64) hb[i] = __float2half(0.0f);

    __syncthreads();   // costab + zero init; the only block barrier

    const int b  = blockIdx.x / BLKS_PER_B_;
    const int g  = (blockIdx.x % BLKS_PER_B_) * WAVES_ + wid;  // group in [0,500)
    const int f0 = g * GF_;

    const int   t     = lane + 1;            // lane computes ir_raw[t], t=1..64
    const float scale = 2.0f / 129.0f;
    const float cA = 0.5f * (1.0f - costab[64 - t]) * scale;   // win[64-t]*(2/129)
    const float cB = 0.5f * (1.0f - costab[64 + t]) * scale;   // win[64+t]*(2/129)
    const float c0 = 0.5f * (1.0f - costab[64]) * scale;       // win[64]  *(2/129)

    // Chebyshev seeds from the exact table (per-lane, once)
    const float c1 = costab[t];
    const float tc = 2.0f * c1;
    float sdA[4], sdB[4];
    sdA[0] = 1.0f;                 sdB[0] = c1;
    sdA[1] = costab[(16*t) % N_];  sdB[1] = costab[(17*t) % N_];
    sdA[2] = costab[(32*t) % N_];  sdB[2] = costab[(33*t) % N_];
    sdA[3] = costab[(48*t) % N_];  sdB[3] = costab[(49*t) % N_];

    const float* Xf = nfilt + (size_t)(b * F_ + f0) * L_;          // uniform
    const float* Zf = noise + (size_t)(b * F_ + f0) * HOP_ + lane; // per-lane
    float*       op = out + (size_t)b * OUTLEN_ + (size_t)f0 * HOP_ + lane;

    __half* hE = &hbuf[wid][0][0];   // tap m at pos m+64
    __half* hO = &hbuf[wid][1][0];   // tap m at pos m+65

    // Per-lane read base: odd lanes use copyE (shift 0), even lanes copyO (+1)
    // so every j-pair dword is aligned with uniform half->j mapping.
    const int soff = (lane & 1) ? 0 : 1;
    const __half* cpsel = (lane & 1) ? hE : hO;
    const __half2* bmin = (const __half2*)cpsel + (((lane + soff + 63) >> 1) - 31);
    // seg s, pair p: dword = bmin[(31-p) + 32*s]; low half = tap(j=2p+1), high = tap(j=2p)

    // rolling accumulators, 2 partial chains each (pair parity)
    float wa[2] = {0,0}, wb[2] = {0,0}, wc[2] = {0,0};

    #pragma unroll 1
    for (int i = 0; i < GF_; ++i) {
        // coalesced per-lane noise load (vmcnt; hidden behind Phase A)
        float zc = Zf[0];
        zc = fmaf(2.0f, zc, -1.0f);

        // ---- Phase A: a = 0.5*X0 + sum_{k=1..64} X[k]*cos(k*t*th) ----
        float x0 = Xf[0];
        float a = 0.5f * x0;
        float s = 0.5f * x0;
        #pragma unroll
        for (int c = 0; c < 4; ++c) {
            float ckm1 = sdA[c], ck = sdB[c];
            float aa = 0.0f, ss = 0.0f;
            #pragma unroll
            for (int q = 0; q < 16; ++q) {
                float x = Xf[c * 16 + q + 1];     // wave-uniform -> s_load
                aa = fmaf(x, ck, aa);
                ss += x;
                float cn = fmaf(tc, ck, -ckm1);   // Chebyshev step
                ckm1 = ck; ck = cn;
            }
            a += aa; s += ss;
        }

        // ---- windowed IR -> f16, both copies; order pinned (cross-lane RAW,
        //      sched_barrier is correctness-critical per R6) ----
        __builtin_amdgcn_sched_barrier(0);
        {
            __half hA = __float2half(cA * a);   // tap 63-lane
            __half hB = __float2half(cB * a);   // tap 65+lane
            hE[127 - lane] = hA;  hE[129 + lane] = hB;
            hO[128 - lane] = hA;  hO[130 + lane] = hB;
            if (lane == 0) {                    // center tap 64
                __half hC = __float2half(c0 * s);
                hE[128] = hC;  hO[129] = hC;
            }
        }
        __builtin_amdgcn_sched_barrier(0);

        // ---- Phase B: 3 dword loads + 6 mixed fma per j-pair ----
        #pragma unroll
        for (int p = 0; p < 32; ++p) {
            const int pc = p & 1;
            float z0 = __uint_as_float(
                __builtin_amdgcn_readlane(__float_as_uint(zc), 2 * p));
            float z1 = __uint_as_float(
                __builtin_amdgcn_readlane(__float_as_uint(zc), 2 * p + 1));
            __half2 v0 = bmin[(31 - p)];        // seg0 (out k=lane)
            __half2 v1 = bmin[(31 - p) + 32];   // seg1 (k=lane+64)
            __half2 v2 = bmin[(31 - p) + 64];   // seg2 (k=lane+128)
            wa[pc] = fmaf(__high2float(v0), z0, wa[pc]);
            wa[pc] = fmaf(__low2float(v0),  z1, wa[pc]);
            wb[pc] = fmaf(__high2float(v1), z0, wb[pc]);
            wb[pc] = fmaf(__low2float(v1),  z1, wb[pc]);
            wc[pc] = fmaf(__high2float(v2), z0, wc[pc]);
            wc[pc] = fmaf(__low2float(v2),  z1, wc[pc]);
        }
        __builtin_amdgcn_sched_barrier(0);   // WAR fence vs next frame's writes

        // ---- retire slot i (i<2 overlaps previous group -> atomic) ----
        float va = (wa[0] + wa[1]) * GAIN_;
        if (i < 2) atomicAdd(op, va); else *op = va;
        op += HOP_;
        wa[0] = wb[0]; wa[1] = wb[1];
        wb[0] = wc[0]; wb[1] = wc[1];
        wc[0] = 0.0f;  wc[1] = 0.0f;
        Xf += L_; Zf += HOP_;
    }
    atomicAdd(op,        (wa[0] + wa[1]) * GAIN_);  // slot 8 (next group's)
    atomicAdd(op + HOP_, (wb[0] + wb[1]) * GAIN_);  // slot 9
}

extern "C" void kernel_launch(void* const* d_in, const int* in_sizes, int n_in,
                              void* d_out, int out_size, void* d_ws, size_t ws_size,
                              hipStream_t stream) {
    const float* nfilt = (const float*)d_in[0];
    const float* noise = (const float*)d_in[1];
    float* out = (float*)d_out;

    hipMemsetAsync(d_out, 0, (size_t)out_size * sizeof(float), stream);

    dim3 grid(B_ * BLKS_PER_B_);   // 4000 blocks
    dim3 block(256);
    filtered_noise_kernel<<<grid, block, 0, stream>>>(nfilt, noise, out);
}